// Round 1
// 192.179 us; speedup vs baseline: 1.0006x; 1.0006x over previous
//
#include <hip/hip_runtime.h>

#define B_ 512
#define T_ 512
#define C_ 128
#define L_ 80
#define BLANK_ 127
#define EPS_ 1e-7f
#define LN2_ 0.6931471805599453f
#define NBLK_ 32   // 8-row blocks per direction (32*8 = 256 rows each)

// raw v_log_f32 (base-2); __log2f collides with glibc math.h reserved names.
#define LOG2F(x) __builtin_amdgcn_logf(x)

// DPP cross-lane ops (VALU pipe — keeps the DS pipe off the critical path).
template <int CTRL>
__device__ __forceinline__ int dpp_i(int x) {
  return __builtin_amdgcn_update_dpp(0, x, CTRL, 0xF, 0xF, true);
}
template <int CTRL>
__device__ __forceinline__ float dpp_f(float x) {
  return __int_as_float(
      __builtin_amdgcn_update_dpp(0, __float_as_int(x), CTRL, 0xF, 0xF, true));
}
#define DPP_WSHR1 0x138   // wave shift right 1 (lane i <- i-1; lane0 -> 0)
#define DPP_WSHL1 0x130   // wave shift left 1  (lane i <- i+1; lane63 -> 0)
#define DPP_XOR1  0xB1    // quad_perm [1,0,3,2]
#define DPP_XOR2  0x4E    // quad_perm [2,3,0,1]
#define DPP_HMIRR 0x141   // row_half_mirror (within 8)
#define DPP_MIRR  0x140   // row_mirror (within 16)

// Producer/consumer + forward/backward split.
//
// 4 waves per workgroup (1 workgroup per batch element, 512 wg = 8 waves/CU):
//   wave0: FORWARD  DP consumer, rows 0..255   -> alpha_255
//   wave1: BACKWARD DP consumer, rows 511..256 -> W_256  (W_t = p_t * beta_t)
//   wave2: producer for fwd ring (loads rows, +EPS, row-sum denominators)
//   wave3: producer for bwd ring
// Identity: P = sum_s alpha_255(s) * beta_255(s),
//   beta_255(s) = W_256(s) + W_256(s+1) + allow2(s+2)*W_256(s+2).
// Linear-domain DP with per-lane scale exponent E (stored = true * 2^E),
// rescaled per 8-step block; neighbor values reconciled with ldexp(d).
// Softmax denominator factors out: loss = ln2*(Sum log2(rowsum_t) - log2 P).
// Sync: double-banked LDS ring per direction, ONE __syncthreads per 8-row
// block (uniform top-level barriers, 34 total). Producers keep a 3-block
// register prefetch pipeline (S0,S1,S2) so HBM latency never touches the
// serial DP chain.
__global__ __launch_bounds__(256) void ctc_fused(
    const int* __restrict__ labels,     // [B,L]
    const float* __restrict__ y_pred,   // [B,T,C]
    float* __restrict__ out)            // [B,1]
{
  const int b = blockIdx.x;
  const int tid = threadIdx.x;
  const int wid = tid >> 6;            // 0 fwd-DP, 1 bwd-DP, 2 fwd-st, 3 bwd-st
  const int lane = tid & 63;
  const float* gp = y_pred + (size_t)b * T_ * C_;

  __shared__ float ring[2 * 2 * 1024]; // [dir][bank][8 rows * 128]
  __shared__ float comb[208];          // beta (192) + Sacc partials (200,201)
  __shared__ int   combE[64];          // backward per-lane exponents

  const bool isCons = (wid < 2);
  const bool isFwd  = (wid == 0);
  const bool evenLane = ((lane & 1) == 0);

  // ---- consumer: static per-lane symbols + skip masks (lane i owns states
  // 3i..3i+2; even lane: blank/label/blank, odd lane: label/blank/label) ----
  int ea = BLANK_, eb = BLANK_;
  float m0 = 0.f, m1 = 0.f, m2 = 0.f;  // fwd: allow2 at (3i,3i+1,3i+2);
                                       // bwd: allow2 at (3i+2,3i+3,3i+4)
  float A0 = 0.f, A1 = 0.f, A2 = 0.f;  // DP state (fwd alpha / bwd W)
  int E = 0;
  if (isCons) {
    auto labAt = [&](int k) -> int {
      return (k >= 0 && k < L_) ? labels[b * L_ + k] : BLANK_;
    };
    if (evenLane) {
      const int k1 = (3 * lane) >> 1;          // label index at state 3i+1
      ea = labAt(k1); eb = ea;
      if (isFwd) {
        m1 = ((k1 < L_) && (k1 == 0 || ea != labAt(k1 - 1))) ? 1.f : 0.f;
      } else {
        // allow2(3i+3): label k1+1 differs from k1
        m1 = ((k1 + 1 < L_) && (labAt(k1 + 1) != ea)) ? 1.f : 0.f;
      }
    } else {
      const int k0 = (3 * lane - 1) >> 1;      // labels at states 3i, 3i+2
      const int k2 = k0 + 1;
      ea = labAt(k0); eb = labAt(k2);
      if (isFwd) {
        m0 = ((k0 < L_) && (k0 == 0 || ea != labAt(k0 - 1))) ? 1.f : 0.f;
        m2 = ((k2 < L_) && (eb != ea)) ? 1.f : 0.f;
      } else {
        m0 = ((k2 < L_) && (eb != ea)) ? 1.f : 0.f;                 // allow2(3i+2)
        m2 = ((k0 + 2 < L_) && (labAt(k0 + 2) != eb)) ? 1.f : 0.f;  // allow2(3i+4)
      }
    }
    // virtual init: one recurrence step reproduces the exact t=0 / t=511 init
    if (isFwd) A0 = (lane == 0) ? 1.f : 0.f;    // pre-state 1 at state 0
    else       A1 = (lane == 53) ? 1.f : 0.f;   // pre-state 1 at state 160
  }

  // ---- producer state ----
  const int dir = wid & 1;             // wave2 -> 0 (fwd rows), wave3 -> 1
  const int rgrp = lane >> 3, j16 = lane & 7;
  float4 S0[4], S1[4], S2[4];
  float Sacc = 0.f;
  float* ringD = ring + dir * 2048;
  const float* ringC = ring + wid * 2048;   // valid for wid<2 only

  auto rowbase = [&](int blk) -> const float4* {
    const int r0 = dir ? (504 - 8 * blk) : (8 * blk);
    return (const float4*)(gp + (size_t)(r0 + rgrp) * C_) + 4 * j16;
  };
  auto loadset = [&](float4 (&S)[4], int blk) {
    const float4* p = rowbase(blk);
    #pragma unroll
    for (int k = 0; k < 4; ++k) S[k] = p[k];
  };
  // eps-add, stage into ring bank, fused row-sum (8-lane DPP reduce) + log2
  auto prep = [&](float4 (&S)[4], int bank) {
    #pragma unroll
    for (int k = 0; k < 4; ++k) {
      S[k].x += EPS_; S[k].y += EPS_; S[k].z += EPS_; S[k].w += EPS_;
    }
    float4* wd = (float4*)(ringD + bank * 1024 + rgrp * C_ + 16 * j16);
    #pragma unroll
    for (int k = 0; k < 4; ++k) wd[k] = S[k];
    float s = 0.f;
    #pragma unroll
    for (int k = 0; k < 4; ++k) s += (S[k].x + S[k].y) + (S[k].z + S[k].w);
    s += dpp_f<DPP_XOR1>(s);
    s += dpp_f<DPP_XOR2>(s);
    s += dpp_f<DPP_HMIRR>(s);           // 8 lanes of a row share the row-sum
    Sacc += LOG2F(s);                   // 8x redundant; divided out at the end
  };

  // ---- consumer: one 8-row block ----
  auto consume = [&](int n) {
    const int bank = n & 1;
    const float* rb = ringC + bank * 1024;
    float ga[8], gb[8], pb[8];
    if (isFwd) {
      const int EL = dpp_i<DPP_WSHR1>(E);
      const int d = E - EL;             // block-constant reconcile shift
      #pragma unroll
      for (int j = 0; j < 8; ++j) {
        ga[j] = rb[j * C_ + ea];
        gb[j] = rb[j * C_ + eb];
        pb[j] = rb[j * C_ + BLANK_];    // same addr all lanes: LDS broadcast
      }
      #pragma unroll
      for (int j = 0; j < 8; ++j) {
        const float p1 = dpp_f<DPP_WSHR1>(A1);   // left A1 (state 3i-2)
        const float p2 = dpp_f<DPP_WSHR1>(A2);   // left A2 (state 3i-1)
        const float p1p = ldexpf(p1, d);
        const float p2p = ldexpf(p2, d);
        const float q0 = evenLane ? pb[j] : ga[j];
        const float q1 = evenLane ? ga[j] : pb[j];
        const float q2 = evenLane ? pb[j] : gb[j];
        const float t0 = q0 * fmaf(m0, p1p, A0 + p2p);
        const float t1 = q1 * fmaf(m1, p2p, A1 + A0);
        const float t2 = q2 * fmaf(m2, A0, A2 + A1);
        A0 = t0; A1 = t1; A2 = t2;
      }
      const float mx = fmaxf(fmaxf(A0, A1), A2);
      int ee = (int)((__float_as_uint(mx) >> 23) & 255u) - 127;
      const bool z = (mx == 0.f);
      ee = z ? 0 : ee;
      A0 = ldexpf(A0, -ee); A1 = ldexpf(A1, -ee); A2 = ldexpf(A2, -ee);
      E = z ? EL : (E - ee);            // virgin lanes track left neighbor's E
    } else {
      const int ER = dpp_i<DPP_WSHL1>(E);
      const int d = E - ER;
      #pragma unroll
      for (int j = 0; j < 8; ++j) {
        const int sl = 7 - j;           // rows consumed in descending t
        ga[j] = rb[sl * C_ + ea];
        gb[j] = rb[sl * C_ + eb];
        pb[j] = rb[sl * C_ + BLANK_];
      }
      #pragma unroll
      for (int j = 0; j < 8; ++j) {
        const float r0 = dpp_f<DPP_WSHL1>(A0);   // right W (state 3i+3)
        const float r1 = dpp_f<DPP_WSHL1>(A1);   // right W (state 3i+4)
        const float r0p = ldexpf(r0, d);
        const float r1p = ldexpf(r1, d);
        const float q0 = evenLane ? pb[j] : ga[j];
        const float q1 = evenLane ? ga[j] : pb[j];
        const float q2 = evenLane ? pb[j] : gb[j];
        const float t0 = q0 * fmaf(m0, A2, A0 + A1);
        const float t1 = q1 * fmaf(m1, r0p, A1 + A2);
        const float t2 = q2 * fmaf(m2, r1p, A2 + r0p);
        A0 = t0; A1 = t1; A2 = t2;
      }
      const float mx = fmaxf(fmaxf(A0, A1), A2);
      int ee = (int)((__float_as_uint(mx) >> 23) & 255u) - 127;
      const bool z = (mx == 0.f);
      ee = z ? 0 : ee;
      A0 = ldexpf(A0, -ee); A1 = ldexpf(A1, -ee); A2 = ldexpf(A2, -ee);
      E = z ? ER : (E - ee);            // virgin lanes track right neighbor's E
    }
  };

  // ---- prologue: preload blocks 0..2, stage block 0, refill S0 with 3 ----
  if (!isCons) {
    loadset(S0, 0); loadset(S1, 1); loadset(S2, 2);
    prep(S0, 0);
    loadset(S0, 3);
  }
  __syncthreads();

  // ---- main loop: iteration n consumes block n (bank n&1); producer preps
  // block n+1 (bank ~n&1) and issues loads for block n+4 (3-block lead) ----
  for (int n = 0; n < 30; n += 3) {
    { if (isCons) consume(n);
      else { prep(S1, (n + 1) & 1); if (n + 4 < NBLK_) loadset(S1, n + 4); } }
    __syncthreads();
    { if (isCons) consume(n + 1);
      else { prep(S2, (n + 2) & 1); if (n + 5 < NBLK_) loadset(S2, n + 5); } }
    __syncthreads();
    { if (isCons) consume(n + 2);
      else { prep(S0, (n + 3) & 1); if (n + 6 < NBLK_) loadset(S0, n + 6); } }
    __syncthreads();
  }
  { if (isCons) consume(30); else prep(S1, 1); }   // block 31 lives in S1
  __syncthreads();
  if (isCons) consume(31);
  __syncthreads();

  // ---- epilogue ----
  if (wid == 1) {
    // beta_255(s) = W(s) + W(s+1) + allow2(s+2)*W(s+2)   (no emission mult)
    const int ER = dpp_i<DPP_WSHL1>(E);
    const int d = E - ER;
    const float r0 = dpp_f<DPP_WSHL1>(A0);
    const float r1 = dpp_f<DPP_WSHL1>(A1);
    const float r0p = ldexpf(r0, d);
    const float r1p = ldexpf(r1, d);
    comb[3 * lane + 0] = fmaf(m0, A2, A0 + A1);
    comb[3 * lane + 1] = fmaf(m1, r0p, A1 + A2);
    comb[3 * lane + 2] = fmaf(m2, r1p, A2 + r0p);
    combE[lane] = E;
  } else if (wid >= 2) {
    // denominator partial (each row counted 8x -> *0.125)
    float s = Sacc;
    s += dpp_f<DPP_XOR1>(s);
    s += dpp_f<DPP_XOR2>(s);
    s += dpp_f<DPP_HMIRR>(s);
    s += dpp_f<DPP_MIRR>(s);
    s += __shfl_xor(s, 16, 64);
    s += __shfl_xor(s, 32, 64);
    if (lane == 0) comb[200 + dir] = s * 0.125f;
  }
  __syncthreads();

  if (wid == 0) {
    // dot: P = sum_s alpha_255(s)*beta_255(s); true = stored * 2^-(EA+EB)
    const float b0 = comb[3 * lane + 0];
    const float b1 = comb[3 * lane + 1];
    const float b2 = comb[3 * lane + 2];
    const int   EB = combE[lane];
    float v = A0 * b0 + A1 * b1 + A2 * b2;   // dead lanes: beta == 0 -> v = 0
    int e = -(E + EB);
    if (v == 0.f) e = -100000000;            // exponent sentinel for zeros
    #pragma unroll
    for (int off = 1; off < 64; off <<= 1) { // (value, exponent) lse-sum tree
      const float v2 = __shfl_xor(v, off, 64);
      const int   e2 = __shfl_xor(e, off, 64);
      const int m = (e > e2) ? e : e2;
      v = ldexpf(v, e - m) + ldexpf(v2, e2 - m);
      e = m;
    }
    if (lane == 0) {
      const float Stot = comb[200] + comb[201];
      out[b] = LN2_ * (Stot - (LOG2F(v) + (float)e));
    }
  }
}

extern "C" void kernel_launch(void* const* d_in, const int* in_sizes, int n_in,
                              void* d_out, int out_size, void* d_ws, size_t ws_size,
                              hipStream_t stream) {
  const int*   labels = (const int*)d_in[0];    // y_true [B,L]
  const float* y_pred = (const float*)d_in[1];  // y_pred [B,T,C]
  float*       out    = (float*)d_out;          // [B,1]
  ctc_fused<<<dim3(B_), dim3(256), 0, stream>>>(labels, y_pred, out);
}